// Round 1
// baseline (2807.239 us; speedup 1.0000x reference)
//
#include <hip/hip_runtime.h>

// GIN 2-layer forward, f32.
// Pipeline (W2 folded before aggregation-2):
//   1. agg1 = node_emb (copy)
//   2. agg1[dst] += node_emb[src]          (atomic scatter, 64-d)
//   3. h = relu(agg1 @ W1 + b1)            (LDS-staged vector GEMM, 64->128)
//   4. g = h @ W2 ; out = g + b2           (LDS-staged vector GEMM, 128->64)
//   5. out[dst] += g[src]                  (atomic scatter, 64-d)
// N=100000 is divisible by 8 and 16, so GEMM row tiles need no tail guard.

__global__ void copy_f4(const float4* __restrict__ in, float4* __restrict__ out, int n4) {
    int i = blockIdx.x * blockDim.x + threadIdx.x;
    if (i < n4) out[i] = in[i];
}

// one thread = one (edge, 4-channel group); 16 consecutive threads cover one edge's 64 channels
__global__ void scatter_add64(const float* __restrict__ x,
                              const int* __restrict__ src,
                              const int* __restrict__ dst,
                              float* __restrict__ agg, int n_edges) {
    int t = blockIdx.x * blockDim.x + threadIdx.x;
    if (t >= n_edges * 16) return;
    int e = t >> 4;
    int c = (t & 15) << 2;
    int s = src[e];
    int d = dst[e];
    const float4 v = *reinterpret_cast<const float4*>(x + (size_t)s * 64 + c);
    float* p = agg + (size_t)d * 64 + c;
    atomicAdd(p + 0, v.x);
    atomicAdd(p + 1, v.y);
    atomicAdd(p + 2, v.z);
    atomicAdd(p + 3, v.w);
}

// h[n,128] = relu(x[n,64] @ W1[64,128] + b1); 8 rows/block, 256 threads
__global__ __launch_bounds__(256) void gemm1_relu(const float* __restrict__ x,
                                                  const float* __restrict__ W1,
                                                  const float* __restrict__ b1,
                                                  float* __restrict__ h, int n) {
    __shared__ float4 Ws[64][32];   // W1 rows as 32 float4 col-groups (32 KiB)
    __shared__ float  xs[8][64];    // 8 input rows (2 KiB); 2-way LDS alias is free
    int t = threadIdx.x;
    const float4* W4 = reinterpret_cast<const float4*>(W1);
    for (int i = t; i < 64 * 32; i += 256) Ws[i >> 5][i & 31] = W4[i];
    int row0 = blockIdx.x * 8;
    const float4* x4 = reinterpret_cast<const float4*>(x + (size_t)row0 * 64);
    float4* xs4 = reinterpret_cast<float4*>(&xs[0][0]);
    if (t < 128) xs4[t] = x4[t];
    __syncthreads();

    int row = t >> 5;   // 0..7
    int cg  = t & 31;   // float4 col group 0..31
    float4 acc = {0.f, 0.f, 0.f, 0.f};
#pragma unroll
    for (int k = 0; k < 64; ++k) {
        float a = xs[row][k];
        float4 w = Ws[k][cg];
        acc.x += a * w.x; acc.y += a * w.y; acc.z += a * w.z; acc.w += a * w.w;
    }
    float4 b = reinterpret_cast<const float4*>(b1)[cg];
    acc.x = fmaxf(acc.x + b.x, 0.f);
    acc.y = fmaxf(acc.y + b.y, 0.f);
    acc.z = fmaxf(acc.z + b.z, 0.f);
    acc.w = fmaxf(acc.w + b.w, 0.f);
    reinterpret_cast<float4*>(h + (size_t)(row0 + row) * 128)[cg] = acc;
}

// g[n,64] = h[n,128] @ W2[128,64]; out = g + b2; 16 rows/block, 256 threads
__global__ __launch_bounds__(256) void gemm2(const float* __restrict__ h,
                                             const float* __restrict__ W2,
                                             const float* __restrict__ b2,
                                             float* __restrict__ g,
                                             float* __restrict__ out, int n) {
    __shared__ float4 Ws[128][16];   // 32 KiB
    __shared__ float  xs[16][132];   // padded: rows land on different banks (8.25 KiB)
    int t = threadIdx.x;
    const float4* W4 = reinterpret_cast<const float4*>(W2);
    for (int i = t; i < 128 * 16; i += 256) Ws[i >> 4][i & 15] = W4[i];
    int row0 = blockIdx.x * 16;
    const float4* x4 = reinterpret_cast<const float4*>(h + (size_t)row0 * 128);
    for (int i = t; i < 512; i += 256) {   // 16 rows * 32 float4
        int r = i >> 5, c = i & 31;
        *reinterpret_cast<float4*>(&xs[r][c * 4]) = x4[i];
    }
    __syncthreads();

    int row = t >> 4;   // 0..15
    int cg  = t & 15;   // float4 col group 0..15
    float4 acc = {0.f, 0.f, 0.f, 0.f};
#pragma unroll
    for (int k = 0; k < 128; ++k) {
        float a = xs[row][k];
        float4 w = Ws[k][cg];
        acc.x += a * w.x; acc.y += a * w.y; acc.z += a * w.z; acc.w += a * w.w;
    }
    size_t o4 = (size_t)(row0 + row) * 16 + cg;
    reinterpret_cast<float4*>(g)[o4] = acc;
    float4 b = reinterpret_cast<const float4*>(b2)[cg];
    float4 ob = {acc.x + b.x, acc.y + b.y, acc.z + b.z, acc.w + b.w};
    reinterpret_cast<float4*>(out)[o4] = ob;
}

extern "C" void kernel_launch(void* const* d_in, const int* in_sizes, int n_in,
                              void* d_out, int out_size, void* d_ws, size_t ws_size,
                              hipStream_t stream) {
    const float* node_emb = (const float*)d_in[0];
    const float* W1 = (const float*)d_in[1];
    const float* b1 = (const float*)d_in[2];
    const float* W2 = (const float*)d_in[3];
    const float* b2 = (const float*)d_in[4];
    const int*   ei = (const int*)d_in[5];   // harness delivers integer inputs as int32
    int n  = in_sizes[0] / 64;
    int ne = in_sizes[5] / 2;
    const int* src = ei;
    const int* dst = ei + ne;
    float* out = (float*)d_out;

    char* ws = (char*)d_ws;
    float* agg1 = (float*)ws;                               // n*64 f32 (25.6 MB), reused as g
    float* h    = (float*)(ws + (size_t)n * 64 * 4);        // n*128 f32 (51.2 MB)
    float* g    = agg1;                                     // agg1 dead after gemm1

    int n4 = n * 16;                                        // n*64/4 float4s
    copy_f4<<<(n4 + 255) / 256, 256, 0, stream>>>((const float4*)node_emb, (float4*)agg1, n4);
    scatter_add64<<<(ne * 16 + 255) / 256, 256, 0, stream>>>(node_emb, src, dst, agg1, ne);
    gemm1_relu<<<(n + 7) / 8, 256, 0, stream>>>(agg1, W1, b1, h, n);
    gemm2<<<(n + 15) / 16, 256, 0, stream>>>(h, W2, b2, g, out, n);
    scatter_add64<<<(ne * 16 + 255) / 256, 256, 0, stream>>>(g, src, dst, out, ne);
}

// Round 2
// 441.434 us; speedup vs baseline: 6.3594x; 6.3594x over previous
//
#include <hip/hip_runtime.h>

// GIN 2-layer forward, f32 — CSR gather instead of atomic scatter.
// Pipeline:
//   build CSR by dst:  hist -> scan(3 kernels) -> bucket (perm[] = src ids)
//   agg1 = x + gather(x)            [gather64]
//   h    = relu(agg1 @ W1 + b1)     [gemm1_relu]
//   g    = h @ W2                   [gemm2]
//   out  = g + b2 + gather(g)       [gather64 with bias]
// (W2 folded before aggregation-2: (A h + h) W2 + b2 = A(hW2) + hW2 + b2.)

__global__ void hist_kernel(const int* __restrict__ dst, int* __restrict__ deg, int ne) {
    int e = blockIdx.x * blockDim.x + threadIdx.x;
    if (e < ne) atomicAdd(&deg[dst[e]], 1);
}

// per-block exclusive scan of deg -> tmp; block totals -> blockSums
__global__ __launch_bounds__(256) void block_scan(const int* __restrict__ deg,
                                                  int* __restrict__ tmp,
                                                  int* __restrict__ blockSums, int n) {
    __shared__ int s[256];
    int t = threadIdx.x;
    int i = blockIdx.x * 256 + t;
    int v = (i < n) ? deg[i] : 0;
    s[t] = v;
    __syncthreads();
    for (int off = 1; off < 256; off <<= 1) {
        int u = (t >= off) ? s[t - off] : 0;
        __syncthreads();
        s[t] += u;
        __syncthreads();
    }
    if (i < n) tmp[i] = s[t] - v;               // exclusive
    if (t == 255) blockSums[blockIdx.x] = s[255];
}

// single-block exclusive scan of blockSums (B <= 512) -> bss
__global__ __launch_bounds__(512) void scan_sums(const int* __restrict__ blockSums,
                                                 int* __restrict__ bss, int B) {
    __shared__ int s[512];
    int t = threadIdx.x;
    int v = (t < B) ? blockSums[t] : 0;
    s[t] = v;
    __syncthreads();
    for (int off = 1; off < 512; off <<= 1) {
        int u = (t >= off) ? s[t - off] : 0;
        __syncthreads();
        s[t] += u;
        __syncthreads();
    }
    if (t < B) bss[t] = s[t] - v;
}

__global__ void finalize_scan(const int* __restrict__ tmp, const int* __restrict__ blockSums,
                              const int* __restrict__ bss, int* __restrict__ off,
                              int* __restrict__ cursor, int n, int B) {
    int i = blockIdx.x * blockDim.x + threadIdx.x;
    if (i < n) {
        int v = tmp[i] + bss[i >> 8];
        off[i] = v;
        cursor[i] = v;
    } else if (i == n) {
        off[n] = bss[B - 1] + blockSums[B - 1];
    }
}

__global__ void bucket_kernel(const int* __restrict__ src, const int* __restrict__ dst,
                              int* __restrict__ cursor, int* __restrict__ perm, int ne) {
    int e = blockIdx.x * blockDim.x + threadIdx.x;
    if (e < ne) {
        int d = dst[e];
        int pos = atomicAdd(&cursor[d], 1);
        perm[pos] = src[e];
    }
}

// out[i] = x[i] + sum_{e in CSR(i)} x[perm[e]]  (+ bias if given)
// 16 threads/node, each owns one float4 channel group; 16 nodes/block.
__global__ __launch_bounds__(256) void gather64(const float4* __restrict__ x4,
                                                const int* __restrict__ off,
                                                const int* __restrict__ perm,
                                                const float* __restrict__ bias,
                                                float4* __restrict__ out4, int n) {
    int t = threadIdx.x;
    int node = blockIdx.x * 16 + (t >> 4);
    int c = t & 15;
    if (node >= n) return;
    int beg = off[node], end = off[node + 1];
    float4 acc = x4[(size_t)node * 16 + c];
    for (int e = beg; e < end; ++e) {
        int s = perm[e];                          // broadcast across the 16-lane group
        float4 v = x4[(size_t)s * 16 + c];
        acc.x += v.x; acc.y += v.y; acc.z += v.z; acc.w += v.w;
    }
    if (bias) {
        float4 b = reinterpret_cast<const float4*>(bias)[c];
        acc.x += b.x; acc.y += b.y; acc.z += b.z; acc.w += b.w;
    }
    out4[(size_t)node * 16 + c] = acc;
}

// h[n,128] = relu(x[n,64] @ W1[64,128] + b1); 8 rows/block, 256 threads
__global__ __launch_bounds__(256) void gemm1_relu(const float* __restrict__ x,
                                                  const float* __restrict__ W1,
                                                  const float* __restrict__ b1,
                                                  float* __restrict__ h, int n) {
    __shared__ float4 Ws[64][32];
    __shared__ float  xs[8][64];
    int t = threadIdx.x;
    const float4* W4 = reinterpret_cast<const float4*>(W1);
    for (int i = t; i < 64 * 32; i += 256) Ws[i >> 5][i & 31] = W4[i];
    int row0 = blockIdx.x * 8;
    const float4* x4 = reinterpret_cast<const float4*>(x + (size_t)row0 * 64);
    float4* xs4 = reinterpret_cast<float4*>(&xs[0][0]);
    if (t < 128) xs4[t] = x4[t];
    __syncthreads();

    int row = t >> 5;
    int cg  = t & 31;
    float4 acc = {0.f, 0.f, 0.f, 0.f};
#pragma unroll
    for (int k = 0; k < 64; ++k) {
        float a = xs[row][k];
        float4 w = Ws[k][cg];
        acc.x += a * w.x; acc.y += a * w.y; acc.z += a * w.z; acc.w += a * w.w;
    }
    float4 b = reinterpret_cast<const float4*>(b1)[cg];
    acc.x = fmaxf(acc.x + b.x, 0.f);
    acc.y = fmaxf(acc.y + b.y, 0.f);
    acc.z = fmaxf(acc.z + b.z, 0.f);
    acc.w = fmaxf(acc.w + b.w, 0.f);
    reinterpret_cast<float4*>(h + (size_t)(row0 + row) * 128)[cg] = acc;
}

// g[n,64] = h[n,128] @ W2[128,64]; 16 rows/block, 256 threads
__global__ __launch_bounds__(256) void gemm2(const float* __restrict__ h,
                                             const float* __restrict__ W2,
                                             float* __restrict__ g, int n) {
    __shared__ float4 Ws[128][16];
    __shared__ float  xs[16][132];
    int t = threadIdx.x;
    const float4* W4 = reinterpret_cast<const float4*>(W2);
    for (int i = t; i < 128 * 16; i += 256) Ws[i >> 4][i & 15] = W4[i];
    int row0 = blockIdx.x * 16;
    const float4* x4 = reinterpret_cast<const float4*>(h + (size_t)row0 * 128);
    for (int i = t; i < 512; i += 256) {
        int r = i >> 5, c = i & 31;
        *reinterpret_cast<float4*>(&xs[r][c * 4]) = x4[i];
    }
    __syncthreads();

    int row = t >> 4;
    int cg  = t & 15;
    float4 acc = {0.f, 0.f, 0.f, 0.f};
#pragma unroll
    for (int k = 0; k < 128; ++k) {
        float a = xs[row][k];
        float4 w = Ws[k][cg];
        acc.x += a * w.x; acc.y += a * w.y; acc.z += a * w.z; acc.w += a * w.w;
    }
    reinterpret_cast<float4*>(g)[(size_t)(row0 + row) * 16 + cg] = acc;
}

extern "C" void kernel_launch(void* const* d_in, const int* in_sizes, int n_in,
                              void* d_out, int out_size, void* d_ws, size_t ws_size,
                              hipStream_t stream) {
    const float* node_emb = (const float*)d_in[0];
    const float* W1 = (const float*)d_in[1];
    const float* b1 = (const float*)d_in[2];
    const float* W2 = (const float*)d_in[3];
    const float* b2 = (const float*)d_in[4];
    const int*   ei = (const int*)d_in[5];
    int n  = in_sizes[0] / 64;
    int ne = in_sizes[5] / 2;
    const int* src = ei;
    const int* dst = ei + ne;
    float* out = (float*)d_out;

    // workspace layout
    char* ws = (char*)d_ws;
    float* agg1 = (float*)ws;                                  // n*64 f32 (25.6 MB), reused as g
    float* h    = (float*)(ws + (size_t)n * 64 * 4);           // n*128 f32 (51.2 MB)
    char*  p    = ws + (size_t)n * 64 * 4 + (size_t)n * 128 * 4;
    int* off       = (int*)p;            p += (size_t)(n + 1) * 4;
    int* cursor    = (int*)p;            p += (size_t)n * 4;
    int* deg       = (int*)p;            p += (size_t)n * 4;
    int* tmp       = (int*)p;            p += (size_t)n * 4;
    int* blockSums = (int*)p;            p += 512 * 4;
    int* bss       = (int*)p;            p += 512 * 4;
    int* perm      = (int*)p;            p += (size_t)ne * 4;
    float* g = agg1;                                           // agg1 dead after gemm1

    int B = (n + 255) / 256;                                   // 391 for n=100000

    hipMemsetAsync(deg, 0, (size_t)n * 4, stream);
    hist_kernel<<<(ne + 255) / 256, 256, 0, stream>>>(dst, deg, ne);
    block_scan<<<B, 256, 0, stream>>>(deg, tmp, blockSums, n);
    scan_sums<<<1, 512, 0, stream>>>(blockSums, bss, B);
    finalize_scan<<<(n + 256) / 256, 256, 0, stream>>>(tmp, blockSums, bss, off, cursor, n, B);
    bucket_kernel<<<(ne + 255) / 256, 256, 0, stream>>>(src, dst, cursor, perm, ne);

    gather64<<<(n + 15) / 16, 256, 0, stream>>>((const float4*)node_emb, off, perm,
                                                nullptr, (float4*)agg1, n);
    gemm1_relu<<<(n + 7) / 8, 256, 0, stream>>>(agg1, W1, b1, h, n);
    gemm2<<<(n + 15) / 16, 256, 0, stream>>>(h, W2, g, n);
    gather64<<<(n + 15) / 16, 256, 0, stream>>>((const float4*)g, off, perm,
                                                b2, (float4*)out, n);
}

// Round 3
// 293.825 us; speedup vs baseline: 9.5541x; 1.5024x over previous
//
#include <hip/hip_runtime.h>

// GIN 2-layer forward, f32 — CSR via two-level counting sort (no hot global atomics).
// Pipeline:
//   bin_hist -> scan_bins -> partition (pack (src<<8)|dstLocal per bin) -> bin_finalize
//   agg1 = x + gather(x)            [gather64]
//   h    = relu(agg1 @ W1 + b1)     [gemm1_relu]
//   g    = h @ W2                   [gemm2]
//   out  = g + b2 + gather(g)       [gather64 with bias]
// (W2 folded before aggregation-2: (A h + h) W2 + b2 = A(hW2) + hW2 + b2.)

#define EPB 4096     // edges per block in bin_hist / partition
#define CAP 6144     // LDS staging cap for bin_finalize (bins avg ~4092 edges)

// per-block LDS histogram of dst>>8, flushed with one global atomic per bin
__global__ __launch_bounds__(256) void bin_hist(const int* __restrict__ dst,
                                                int* __restrict__ binCnt, int ne, int nbins) {
    __shared__ int h[512];
    int t = threadIdx.x;
    for (int i = t; i < nbins; i += 256) h[i] = 0;
    __syncthreads();
    int eb = blockIdx.x * EPB;
#pragma unroll
    for (int i = 0; i < 16; ++i) {
        int e = eb + t + i * 256;
        if (e < ne) atomicAdd(&h[dst[e] >> 8], 1);
    }
    __syncthreads();
    for (int i = t; i < nbins; i += 256) if (h[i]) atomicAdd(&binCnt[i], h[i]);
}

// single-block exclusive scan of binCnt (nbins <= 512)
__global__ __launch_bounds__(512) void scan_bins(const int* __restrict__ binCnt,
                                                 int* __restrict__ binOff, int* __restrict__ binCur,
                                                 int* __restrict__ off, int nbins, int n, int ne) {
    __shared__ int s[512];
    int t = threadIdx.x;
    int v = (t < nbins) ? binCnt[t] : 0;
    s[t] = v;
    __syncthreads();
    for (int o = 1; o < 512; o <<= 1) {
        int u = (t >= o) ? s[t - o] : 0;
        __syncthreads();
        s[t] += u;
        __syncthreads();
    }
    if (t < nbins) { int b = s[t] - v; binOff[t] = b; binCur[t] = b; }
    if (t == 0) { binOff[nbins] = ne; off[n] = ne; }
}

// scatter edges into bin regions; entry = (src<<8) | (dst & 255)
__global__ __launch_bounds__(256) void partition(const int* __restrict__ src,
                                                 const int* __restrict__ dst,
                                                 int* __restrict__ binCur,
                                                 unsigned* __restrict__ part, int ne, int nbins) {
    __shared__ int h[512];
    __shared__ int base[512];
    int t = threadIdx.x;
    for (int i = t; i < nbins; i += 256) h[i] = 0;
    __syncthreads();
    int eb = blockIdx.x * EPB;
    int ss[16], ds[16];
#pragma unroll
    for (int i = 0; i < 16; ++i) {
        int e = eb + t + i * 256;
        if (e < ne) { ss[i] = src[e]; ds[i] = dst[e]; atomicAdd(&h[ds[i] >> 8], 1); }
        else ds[i] = -1;
    }
    __syncthreads();
    for (int i = t; i < nbins; i += 256) base[i] = h[i] ? atomicAdd(&binCur[i], h[i]) : 0;
    __syncthreads();
    for (int i = t; i < nbins; i += 256) h[i] = 0;   // reuse as local cursor
    __syncthreads();
#pragma unroll
    for (int i = 0; i < 16; ++i) {
        if (ds[i] >= 0) {
            int b = ds[i] >> 8;
            int p = atomicAdd(&h[b], 1);
            part[base[b] + p] = ((unsigned)ss[i] << 8) | (unsigned)(ds[i] & 255);
        }
    }
}

// one block per bin: LDS-stage its edges, local hist+scan, emit perm[] and off[]
__global__ __launch_bounds__(256) void bin_finalize(const unsigned* __restrict__ part,
                                                    const int* __restrict__ binOff,
                                                    int* __restrict__ off, int* __restrict__ perm,
                                                    int n, int nbins) {
    __shared__ unsigned st[CAP];
    __shared__ int cnt[256], ex[256], cur[256];
    int b = blockIdx.x;
    int t = threadIdx.x;
    int e0 = binOff[b], e1 = binOff[b + 1];
    int m = e1 - e0;
    int nb0 = b << 8;
    int nn = min(256, n - nb0);
    cnt[t] = 0;
    __syncthreads();
    bool staged = (m <= CAP);
    if (staged) {
        for (int i = t; i < m; i += 256) { unsigned v = part[e0 + i]; st[i] = v; atomicAdd(&cnt[v & 255u], 1); }
    } else {
        for (int i = t; i < m; i += 256) { unsigned v = part[e0 + i]; atomicAdd(&cnt[v & 255u], 1); }
    }
    __syncthreads();
    int v = cnt[t];
    ex[t] = v;
    __syncthreads();
    for (int o = 1; o < 256; o <<= 1) {
        int u = (t >= o) ? ex[t - o] : 0;
        __syncthreads();
        ex[t] += u;
        __syncthreads();
    }
    int excl = ex[t] - v;
    if (t < nn) off[nb0 + t] = e0 + excl;
    cur[t] = excl;
    __syncthreads();
    if (staged) {
        for (int i = t; i < m; i += 256) {
            unsigned w = st[i];
            int p = atomicAdd(&cur[w & 255u], 1);
            perm[e0 + p] = (int)(w >> 8);
        }
    } else {
        for (int i = t; i < m; i += 256) {
            unsigned w = part[e0 + i];
            int p = atomicAdd(&cur[w & 255u], 1);
            perm[e0 + p] = (int)(w >> 8);
        }
    }
}

// out[i] = x[i] + sum_{e in CSR(i)} x[perm[e]]  (+ bias if given)
__global__ __launch_bounds__(256) void gather64(const float4* __restrict__ x4,
                                                const int* __restrict__ off,
                                                const int* __restrict__ perm,
                                                const float* __restrict__ bias,
                                                float4* __restrict__ out4, int n) {
    int t = threadIdx.x;
    int node = blockIdx.x * 16 + (t >> 4);
    int c = t & 15;
    if (node >= n) return;
    int beg = off[node], end = off[node + 1];
    float4 acc = x4[(size_t)node * 16 + c];
    for (int e = beg; e < end; ++e) {
        int s = perm[e];
        float4 v = x4[(size_t)s * 16 + c];
        acc.x += v.x; acc.y += v.y; acc.z += v.z; acc.w += v.w;
    }
    if (bias) {
        float4 bb = reinterpret_cast<const float4*>(bias)[c];
        acc.x += bb.x; acc.y += bb.y; acc.z += bb.z; acc.w += bb.w;
    }
    out4[(size_t)node * 16 + c] = acc;
}

// h[n,128] = relu(x[n,64] @ W1[64,128] + b1); 8 rows/block
__global__ __launch_bounds__(256) void gemm1_relu(const float* __restrict__ x,
                                                  const float* __restrict__ W1,
                                                  const float* __restrict__ b1,
                                                  float* __restrict__ h, int n) {
    __shared__ float4 Ws[64][32];
    __shared__ float  xs[8][64];
    int t = threadIdx.x;
    const float4* W4 = reinterpret_cast<const float4*>(W1);
    for (int i = t; i < 64 * 32; i += 256) Ws[i >> 5][i & 31] = W4[i];
    int row0 = blockIdx.x * 8;
    const float4* x4 = reinterpret_cast<const float4*>(x + (size_t)row0 * 64);
    float4* xs4 = reinterpret_cast<float4*>(&xs[0][0]);
    if (t < 128) xs4[t] = x4[t];
    __syncthreads();

    int row = t >> 5;
    int cg  = t & 31;
    float4 acc = {0.f, 0.f, 0.f, 0.f};
#pragma unroll
    for (int k = 0; k < 64; ++k) {
        float a = xs[row][k];
        float4 w = Ws[k][cg];
        acc.x += a * w.x; acc.y += a * w.y; acc.z += a * w.z; acc.w += a * w.w;
    }
    float4 b = reinterpret_cast<const float4*>(b1)[cg];
    acc.x = fmaxf(acc.x + b.x, 0.f);
    acc.y = fmaxf(acc.y + b.y, 0.f);
    acc.z = fmaxf(acc.z + b.z, 0.f);
    acc.w = fmaxf(acc.w + b.w, 0.f);
    reinterpret_cast<float4*>(h + (size_t)(row0 + row) * 128)[cg] = acc;
}

// g[n,64] = h[n,128] @ W2[128,64]; 16 rows/block
__global__ __launch_bounds__(256) void gemm2(const float* __restrict__ h,
                                             const float* __restrict__ W2,
                                             float* __restrict__ g, int n) {
    __shared__ float4 Ws[128][16];
    __shared__ float  xs[16][132];
    int t = threadIdx.x;
    const float4* W4 = reinterpret_cast<const float4*>(W2);
    for (int i = t; i < 128 * 16; i += 256) Ws[i >> 4][i & 15] = W4[i];
    int row0 = blockIdx.x * 16;
    const float4* x4 = reinterpret_cast<const float4*>(h + (size_t)row0 * 128);
    for (int i = t; i < 512; i += 256) {
        int r = i >> 5, c = i & 31;
        *reinterpret_cast<float4*>(&xs[r][c * 4]) = x4[i];
    }
    __syncthreads();

    int row = t >> 4;
    int cg  = t & 15;
    float4 acc = {0.f, 0.f, 0.f, 0.f};
#pragma unroll
    for (int k = 0; k < 128; ++k) {
        float a = xs[row][k];
        float4 w = Ws[k][cg];
        acc.x += a * w.x; acc.y += a * w.y; acc.z += a * w.z; acc.w += a * w.w;
    }
    reinterpret_cast<float4*>(g)[(size_t)(row0 + row) * 16 + cg] = acc;
}

extern "C" void kernel_launch(void* const* d_in, const int* in_sizes, int n_in,
                              void* d_out, int out_size, void* d_ws, size_t ws_size,
                              hipStream_t stream) {
    const float* node_emb = (const float*)d_in[0];
    const float* W1 = (const float*)d_in[1];
    const float* b1 = (const float*)d_in[2];
    const float* W2 = (const float*)d_in[3];
    const float* b2 = (const float*)d_in[4];
    const int*   ei = (const int*)d_in[5];
    int n  = in_sizes[0] / 64;
    int ne = in_sizes[5] / 2;
    const int* src = ei;
    const int* dst = ei + ne;
    float* out = (float*)d_out;

    int nbins = (n + 255) >> 8;   // 391

    // workspace layout (part aliases h: part is dead before gemm1 writes h)
    char* ws = (char*)d_ws;
    float* agg1 = (float*)ws;                                  // n*64 f32, reused as g
    float* h    = (float*)(ws + (size_t)n * 64 * 4);           // n*128 f32
    unsigned* part = (unsigned*)h;                             // ne u32 (alias, dead by gemm1)
    char*  p    = ws + (size_t)n * 64 * 4 + (size_t)n * 128 * 4;
    int* off    = (int*)p;            p += (size_t)(n + 1) * 4;
    int* perm   = (int*)p;            p += (size_t)ne * 4;
    int* binCnt = (int*)p;            p += (size_t)(nbins + 1) * 4;
    int* binOff = (int*)p;            p += (size_t)(nbins + 1) * 4;
    int* binCur = (int*)p;            p += (size_t)(nbins + 1) * 4;
    float* g = agg1;                                           // agg1 dead after gemm1

    int nblk = (ne + EPB - 1) / EPB;   // 391

    hipMemsetAsync(binCnt, 0, (size_t)nbins * 4, stream);
    bin_hist<<<nblk, 256, 0, stream>>>(dst, binCnt, ne, nbins);
    scan_bins<<<1, 512, 0, stream>>>(binCnt, binOff, binCur, off, nbins, n, ne);
    partition<<<nblk, 256, 0, stream>>>(src, dst, binCur, part, ne, nbins);
    bin_finalize<<<nbins, 256, 0, stream>>>(part, binOff, off, perm, n, nbins);

    gather64<<<(n + 15) / 16, 256, 0, stream>>>((const float4*)node_emb, off, perm,
                                                nullptr, (float4*)agg1, n);
    gemm1_relu<<<(n + 7) / 8, 256, 0, stream>>>(agg1, W1, b1, h, n);
    gemm2<<<(n + 15) / 16, 256, 0, stream>>>(h, W2, g, n);
    gather64<<<(n + 15) / 16, 256, 0, stream>>>((const float4*)g, off, perm,
                                                b2, (float4*)out, n);
}